// Round 16
// baseline (224.305 us; speedup 1.0000x reference)
//
#include <hip/hip_runtime.h>
#include <hip/hip_bf16.h>

// WeightedLoss round 16: 32x64 wave tiles under the 128-reg quantum.
// r15 analysis: both gram kernels are latency-bound at 2 waves/SIMD because
// 76 VGPR + 64 AGPR ~ 140/wave lands in the 256-reg allocation quantum
// (occupancy steps at 64/128/256 — m69). This round: 512-thread blocks,
// 8 waves of 32x64 (acc 32 AGPR + frags 24 VGPR + misc ~ 91 regs <= 128)
// with __launch_bounds__(512,4) -> 4 waves/SIMD, double latency hiding.
// Packed-fragment layout (single base + constant offsets, no pointer
// arrays), private-LDS sim park in loss, supertile ordering, coalesced prep.
// ws: [0] Obp bf16 packed 4 MB | [4194304] Lnp bf16 packed 2 MB
//     [6291456] sq f32 | [6324224] pos_sums | [6356992] neg_sums
//     [6389760] stats u32[3]

#define B_N 8192
#define NT   64
#define TILE 128
#define NTRI 2080

typedef __attribute__((ext_vector_type(8))) short bf16x8;
typedef __attribute__((ext_vector_type(4))) float f32x4;
typedef __attribute__((ext_vector_type(2))) _Float16 f16x2;

__device__ __forceinline__ unsigned fenc(float f) {
    unsigned u = __float_as_uint(f);
    return (u & 0x80000000u) ? ~u : (u | 0x80000000u);
}
__device__ __forceinline__ float fdec(unsigned k) {
    unsigned u = (k & 0x80000000u) ? (k ^ 0x80000000u) : ~k;
    return __uint_as_float(u);
}
__device__ __forceinline__ unsigned pack2(float a, float b) {
    f16x2 p; p[0] = (_Float16)a; p[1] = (_Float16)b;
    return *(unsigned*)&p;
}

// Supertile decode: 4 diagonal 16x16-tri supertiles (136 tiles each, b<544),
// then 6 off-diagonal 16x16 supertiles (256 tiles each). bi<=bj always.
__device__ __forceinline__ void tile_decode(int b, int& bi, int& bj) {
    int si, sj, ti, tj;
    if (b < 544) {
        int sb = b / 136, w = b - sb * 136;
        int i = 0;
        while (w >= 16 - i) { w -= 16 - i; i++; }
        si = sb; sj = sb; ti = i; tj = i + w;
    } else {
        int q = (b - 544) >> 8, w = (b - 544) & 255;
        int i = 0;
        while (q >= 3 - i) { q -= 3 - i; i++; }
        si = i; sj = i + 1 + q;
        ti = w >> 4; tj = w & 15;
    }
    bi = si * 16 + ti; bj = sj * 16 + tj;
}

// ---------------------------------------------------------------- prep ----
// One block per 16-row group g. LDS transpose -> contiguous packed writes.
__global__ __launch_bounds__(256) void prep_kernel(
    const float* __restrict__ outputs, const float* __restrict__ labels,
    __hip_bfloat16* __restrict__ Obp, __hip_bfloat16* __restrict__ Lnp,
    float* __restrict__ sq, float* __restrict__ pos_sums,
    float* __restrict__ neg_sums, unsigned* __restrict__ stats) {
    int g = blockIdx.x, tid = threadIdx.x;
    int rl = tid >> 4, c = tid & 15;
    int row = g * 16 + rl;
    __shared__ __align__(16) short tO[16][264];
    __shared__ __align__(16) short tL[16][136];

    float s = 0.f;
    #pragma unroll
    for (int k = 0; k < 4; k++) {
        f32x4 v = *(const f32x4*)&outputs[(size_t)row * 256 + c * 16 + k * 4];
        s += v[0]*v[0] + v[1]*v[1] + v[2]*v[2] + v[3]*v[3];
        __hip_bfloat16 b4[4];
        #pragma unroll
        for (int i = 0; i < 4; i++) b4[i] = __float2bfloat16(v[i]);
        *(uint2*)&tO[rl][c * 16 + k * 4] = *(uint2*)b4;
    }
    #pragma unroll
    for (int m = 1; m < 16; m <<= 1) s += __shfl_xor(s, m);
    if (c == 0) sq[row] = s;

    float ls = 0.f;
    f32x4 u0 = *(const f32x4*)&labels[(size_t)row * 128 + c * 8];
    f32x4 u1 = *(const f32x4*)&labels[(size_t)row * 128 + c * 8 + 4];
    ls += u0[0]*u0[0] + u0[1]*u0[1] + u0[2]*u0[2] + u0[3]*u0[3];
    ls += u1[0]*u1[0] + u1[1]*u1[1] + u1[2]*u1[2] + u1[3]*u1[3];
    #pragma unroll
    for (int m = 1; m < 16; m <<= 1) ls += __shfl_xor(ls, m);
    float inv = 1.f / (sqrtf(ls) + 1e-12f);
    {
        __hip_bfloat16 b4[4];
        #pragma unroll
        for (int i = 0; i < 4; i++) b4[i] = __float2bfloat16(u0[i] * inv);
        *(uint2*)&tL[rl][c * 8] = *(uint2*)b4;
        #pragma unroll
        for (int i = 0; i < 4; i++) b4[i] = __float2bfloat16(u1[i] * inv);
        *(uint2*)&tL[rl][c * 8 + 4] = *(uint2*)b4;
    }
    if (tid < 16) { pos_sums[g * 16 + tid] = 0.f; neg_sums[g * 16 + tid] = 0.f; }
    if (g == 0 && tid == 0) {
        stats[0] = 0xFFFFFFFFu; stats[1] = 0u; stats[2] = 0u;
    }
    __syncthreads();

    #pragma unroll
    for (int q = 0; q < 2; q++) {
        int sl = tid * 2 + q;
        int o = sl >> 4, rr = sl & 15;
        uint4 d = *(uint4*)&tO[rr][o * 8];
        *(uint4*)&Obp[(size_t)g * 4096 + (size_t)sl * 8] = d;
    }
    {
        int o = tid >> 4, rr = tid & 15;
        uint4 d = *(uint4*)&tL[rr][o * 8];
        *(uint4*)&Lnp[(size_t)g * 2048 + (size_t)tid * 8] = d;
    }
}

// --------------------------------- packed direct-global 32x64 wave gram ----
// KD8 = K/8 (16 for Ln, 32 for Ob). Fragment slot (rb16+mi)*KD8*16 +
// kc*64 + lane -> one coalesced 1-KB dwordx4 per wave. acc = 32 AGPRs.
template<int KD8>
__device__ __forceinline__ void gram32(
    const short* __restrict__ P, int rb16, int cb16, int lane,
    f32x4 (&acc)[2][4]) {
    #pragma unroll
    for (int mi = 0; mi < 2; mi++)
        #pragma unroll
        for (int ni = 0; ni < 4; ni++) {
            f32x4 z = {0.f, 0.f, 0.f, 0.f};
            acc[mi][ni] = z;
        }
    #pragma unroll
    for (int kc = 0; kc < KD8 / 4; kc++) {
        bf16x8 a[2], b[4];
        #pragma unroll
        for (int mi = 0; mi < 2; mi++)
            a[mi] = *(const bf16x8*)&P[((size_t)(rb16 + mi) * KD8 * 16
                                        + kc * 64 + lane) * 8];
        #pragma unroll
        for (int ni = 0; ni < 4; ni++)
            b[ni] = *(const bf16x8*)&P[((size_t)(cb16 + ni) * KD8 * 16
                                        + kc * 64 + lane) * 8];
        #pragma unroll
        for (int mi = 0; mi < 2; mi++)
            #pragma unroll
            for (int ni = 0; ni < 4; ni++)
                acc[mi][ni] = __builtin_amdgcn_mfma_f32_16x16x32_bf16(
                    a[mi], b[ni], acc[mi][ni], 0, 0, 0);
    }
}

// ---------------------------------------------------------------- stats ----
// 512 threads = 8 waves of 32x64 (4 row-bands x 2 col-halves).
__global__ __launch_bounds__(512, 4) void stats_kernel(
    const short* __restrict__ Lnp, const short* __restrict__ Obp,
    const float* __restrict__ sq, unsigned* __restrict__ stats) {
    int bi, bj;
    tile_decode(blockIdx.x, bi, bj);
    int tid = threadIdx.x, lane = tid & 63, wid = tid >> 6;
    int wb = wid >> 1, wc = wid & 1;
    int wm = wb * 32, wn = wc * 64;
    int l15 = lane & 15, quad = lane >> 4;
    int rb16 = bi * 8 + wb * 2, cb16 = bj * 8 + wc * 4;
    int rB = bi * TILE, cB = bj * TILE;

    float lmin = 1e30f, lmax = -1e30f, dmax = 0.f;
    f32x4 acc[2][4];

    gram32<16>(Lnp, rb16, cb16, lane, acc);
    #pragma unroll
    for (int mi = 0; mi < 2; mi++)
        #pragma unroll
        for (int ni = 0; ni < 4; ni++)
            #pragma unroll
            for (int r = 0; r < 4; r++) {
                float s = acc[mi][ni][r];
                lmin = fminf(lmin, s);
                lmax = fmaxf(lmax, s);
            }

    gram32<32>(Obp, rb16, cb16, lane, acc);
    float sqj[4];
    #pragma unroll
    for (int ni = 0; ni < 4; ni++) sqj[ni] = sq[cB + wn + ni * 16 + l15];
    #pragma unroll
    for (int mi = 0; mi < 2; mi++) {
        f32x4 sqi = *(const f32x4*)&sq[rB + wm + mi * 16 + quad * 4];
        #pragma unroll
        for (int r = 0; r < 4; r++)
            #pragma unroll
            for (int ni = 0; ni < 4; ni++) {
                float d2 = fmaxf(sqi[r] + sqj[ni] - 2.f * acc[mi][ni][r], 0.f);
                dmax = fmaxf(dmax, d2);
            }
    }

    #pragma unroll
    for (int m = 1; m < 64; m <<= 1) {
        lmin = fminf(lmin, __shfl_xor(lmin, m));
        lmax = fmaxf(lmax, __shfl_xor(lmax, m));
        dmax = fmaxf(dmax, __shfl_xor(dmax, m));
    }
    __shared__ float red[3][8];
    if ((tid & 63) == 0) { red[0][wid] = lmin; red[1][wid] = lmax; red[2][wid] = dmax; }
    __syncthreads();
    if (tid == 0) {
        #pragma unroll
        for (int w = 1; w < 8; w++) {
            red[0][0] = fminf(red[0][0], red[0][w]);
            red[1][0] = fmaxf(red[1][0], red[1][w]);
            red[2][0] = fmaxf(red[2][0], red[2][w]);
        }
        atomicMin(&stats[0], fenc(red[0][0]));
        atomicMax(&stats[1], fenc(red[1][0]));
        atomicMax(&stats[2], fenc(red[2][0]));
    }
}

// ----------------------------------------------------------------- loss ----
// gram S -> park raw sim in private LDS slot (16 u32/lane, no barrier) ->
// gram G into the SAME acc regs -> fused epilogue with row+col sums.
__global__ __launch_bounds__(512, 4) void loss_kernel(
    const short* __restrict__ Lnp, const short* __restrict__ Obp,
    const float* __restrict__ sq, const unsigned* __restrict__ stats,
    float* __restrict__ pos_sums, float* __restrict__ neg_sums) {
    int bi, bj;
    tile_decode(blockIdx.x, bi, bj);
    int tid = threadIdx.x, lane = tid & 63, wid = tid >> 6;
    int wb = wid >> 1, wc = wid & 1;
    int wm = wb * 32, wn = wc * 64;
    int l15 = lane & 15, quad = lane >> 4;
    int rb16 = bi * 8 + wb * 2, cb16 = bj * 8 + wc * 4;
    int rB = bi * TILE, cB = bj * TILE;

    __shared__ unsigned simW[512 * 18];   // 36 KB: 72 B per thread (64 used)
    __shared__ float rP[TILE][2], rN[TILE][2];
    __shared__ float cP[TILE][4], cN[TILE][4];
    unsigned* my = &simW[tid * 18];

    f32x4 acc[2][4];

    // --- sim gram; park raw sim in private LDS slot ---
    gram32<16>(Lnp, rb16, cb16, lane, acc);
    #pragma unroll
    for (int mi = 0; mi < 2; mi++)
        #pragma unroll
        for (int ni = 0; ni < 4; ni++) {
            my[(mi * 4 + ni) * 2 + 0] = pack2(acc[mi][ni][0], acc[mi][ni][1]);
            my[(mi * 4 + ni) * 2 + 1] = pack2(acc[mi][ni][2], acc[mi][ni][3]);
        }

    // --- outputs gram (same acc registers) ---
    gram32<32>(Obp, rb16, cb16, lane, acc);

    float smin = fdec(stats[0]);
    float smax = fdec(stats[1]);
    float d2max = fdec(stats[2]);
    float invr = 1.f / (smax - smin);
    float invem = rsqrtf(d2max);

    float sqj[4];
    #pragma unroll
    for (int ni = 0; ni < 4; ni++) sqj[ni] = sq[cB + wn + ni * 16 + l15];
    float cpsum[4] = {0.f, 0.f, 0.f, 0.f};
    float cnsum[4] = {0.f, 0.f, 0.f, 0.f};

    #pragma unroll
    for (int mi = 0; mi < 2; mi++) {
        f32x4 sqi = *(const f32x4*)&sq[rB + wm + mi * 16 + quad * 4];
        float ps[4] = {0.f, 0.f, 0.f, 0.f};
        float ns[4] = {0.f, 0.f, 0.f, 0.f};
        #pragma unroll
        for (int ni = 0; ni < 4; ni++) {
            f16x2 s01 = ((const f16x2*)my)[(mi * 4 + ni) * 2 + 0];
            f16x2 s23 = ((const f16x2*)my)[(mi * 4 + ni) * 2 + 1];
            #pragma unroll
            for (int r = 0; r < 4; r++) {
                float sraw = (r < 2) ? (float)s01[r] : (float)s23[r - 2];
                float sn = (sraw - smin) * invr;
                float g = acc[mi][ni][r];
                float d2 = fmaxf(sqi[r] + sqj[ni] - 2.f * g, 0.f);
                float eud = (d2 > 0.f) ? sqrtf(d2) * invem : 0.f;
                float dist = eud + sn;
                bool pos = sn > 0.5f;   // TAU
                float pv = pos ? __expf(dist) : 0.f;
                float nv = pos ? 0.f : __expf(1.0f - dist);  // MAG = 1
                ps[r] += pv;  ns[r] += nv;
                cpsum[ni] += pv;  cnsum[ni] += nv;
            }
        }
        #pragma unroll
        for (int r = 0; r < 4; r++) {
            #pragma unroll
            for (int m = 1; m < 16; m <<= 1) {
                ps[r] += __shfl_xor(ps[r], m);
                ns[r] += __shfl_xor(ns[r], m);
            }
            if (l15 == 0) {
                int rr = wm + mi * 16 + quad * 4 + r;
                rP[rr][wc] = ps[r];
                rN[rr][wc] = ns[r];
            }
        }
    }
    #pragma unroll
    for (int ni = 0; ni < 4; ni++) {
        #pragma unroll
        for (int m = 16; m < 64; m <<= 1) {
            cpsum[ni] += __shfl_xor(cpsum[ni], m);
            cnsum[ni] += __shfl_xor(cnsum[ni], m);
        }
        if (quad == 0) {
            int cc = wn + ni * 16 + l15;
            cP[cc][wb] = cpsum[ni];
            cN[cc][wb] = cnsum[ni];
        }
    }
    __syncthreads();
    if (tid < TILE) {
        atomicAdd(&pos_sums[bi * TILE + tid], rP[tid][0] + rP[tid][1]);
        atomicAdd(&neg_sums[bi * TILE + tid], rN[tid][0] + rN[tid][1]);
        if (bi != bj) {
            atomicAdd(&pos_sums[bj * TILE + tid],
                      (cP[tid][0] + cP[tid][1]) + (cP[tid][2] + cP[tid][3]));
            atomicAdd(&neg_sums[bj * TILE + tid],
                      (cN[tid][0] + cN[tid][1]) + (cN[tid][2] + cN[tid][3]));
        }
    }
}

// ------------------------------------------------------------- finalize ----
__global__ __launch_bounds__(256) void finalize_kernel(
    const float* __restrict__ pos_sums, const float* __restrict__ neg_sums,
    float* __restrict__ out) {
    int t = threadIdx.x;
    float acc = 0.f;
    for (int i = t; i < B_N; i += 256) {
        float p = pos_sums[i], n = neg_sums[i];
        float pl = fmaxf(logf(p), 0.f);
        float nl = (n > 0.f) ? fmaxf(logf(n), 0.f) : 0.f;
        acc += pl + nl;
    }
    #pragma unroll
    for (int m = 1; m < 64; m <<= 1) acc += __shfl_xor(acc, m);
    __shared__ float w4[4];
    if ((t & 63) == 0) w4[t >> 6] = acc;
    __syncthreads();
    if (t == 0) out[0] = (w4[0] + w4[1] + w4[2] + w4[3]) / (float)B_N;
}

// ------------------------------------------------------------------ entry ----
extern "C" void kernel_launch(void* const* d_in, const int* in_sizes, int n_in,
                              void* d_out, int out_size, void* d_ws, size_t ws_size,
                              hipStream_t stream) {
    const float* outputs = (const float*)d_in[0];
    const float* labels  = (const float*)d_in[1];
    float* out = (float*)d_out;
    char* ws = (char*)d_ws;
    __hip_bfloat16* Obp = (__hip_bfloat16*)(ws);
    __hip_bfloat16* Lnp = (__hip_bfloat16*)(ws + 4194304);
    float* sq           = (float*)(ws + 6291456);
    float* pos_sums     = (float*)(ws + 6324224);
    float* neg_sums     = (float*)(ws + 6356992);
    unsigned* stats     = (unsigned*)(ws + 6389760);

    prep_kernel<<<B_N / 16, 256, 0, stream>>>(outputs, labels, Obp, Lnp, sq,
                                              pos_sums, neg_sums, stats);
    stats_kernel<<<NTRI, 512, 0, stream>>>((const short*)Lnp, (const short*)Obp,
                                           sq, stats);
    loss_kernel<<<NTRI, 512, 0, stream>>>((const short*)Lnp, (const short*)Obp,
                                          sq, stats, pos_sums, neg_sums);
    finalize_kernel<<<1, 256, 0, stream>>>(pos_sums, neg_sums, out);
}